// Round 7
// baseline (1878.731 us; speedup 1.0000x reference)
//
#include <hip/hip_runtime.h>
#include <hip/hip_fp16.h>
#include <hip/hip_cooperative_groups.h>
#include <math.h>

namespace cg = cooperative_groups;

// LinearCaps2d, BATCH=256, N = B_TYPES*H*W = 2048, C=10, POSE=16, 3 routing iters.
// R19: fused persistent kernel with R17's three failure causes fixed.
// Evidence base (R12-R18): per-pass time invariant to grid split, softmax
// presence, atomic count, staging mechanism; all pipes <26% -> latency x
// concurrency bound. Only lever left that cuts TOTAL work: stage weights+poses
// ONCE for all 3 passes and kill the ~50us of inter-kernel launch gaps.
// vs R17: (1) 512 blocks x 512 thr, LDS 51200 B -> 3 blocks/CU capacity for a
// 2-avg grid (R17 was exact-fit 1/CU: no margin, rag, 41ms sync outlier);
// (2) Ws stays the VERIFIED zero-conflict f16 [rows][16] swizzled layout
// (R17's relayout caused 983k conflicts; R18's f32 version 1.31M);
// (3) poses in 16 VGPR/lane (R18-verified mapping) -> no xs buffer at all;
// (4) __launch_bounds__(512,4) = the proven 128-reg no-spill cap.
// Fallback if coop launch rejected: same kernel as 3 single-pass launches + epi.
// ws: s0,s1,s2 [40960] f32 (491 KB).

typedef _Float16 f16;
typedef _Float16 f16x2 __attribute__((ext_vector_type(2)));
typedef _Float16 f16x4 __attribute__((ext_vector_type(4)));
typedef __fp16   h16x2 __attribute__((ext_vector_type(2)));
typedef float f32x4 __attribute__((ext_vector_type(4)));

__device__ __forceinline__ f16x2 pk(float a, float b) {
    h16x2 t = __builtin_amdgcn_cvt_pkrtz(a, b);
    return __builtin_bit_cast(f16x2, t);
}

#if __has_builtin(__builtin_amdgcn_fdot2)
__device__ __forceinline__ float FDOT2(f16x2 a, f16x2 b, float c) {
    return __builtin_amdgcn_fdot2(__builtin_bit_cast(h16x2, a),
                                  __builtin_bit_cast(h16x2, b), c, false);
}
#else
__device__ __forceinline__ float FDOT2(f16x2 a, f16x2 b, float c) {
    return c + (float)a[0] * (float)b[0] + (float)a[1] * (float)b[1];
}
#endif

__device__ __forceinline__ float xorsum4(float v) {
    v += __shfl_xor(v, 16, 64);
    v += __shfl_xor(v, 32, 64);
    return v;
}

// packed f16x2 cross-quad reduction: one shfl pair for two c's (verified R11)
__device__ __forceinline__ f16x2 xorsum4h(f16x2 v) {
    union { f16x2 h; int i; } u;
    union { int i; f16x2 h; } w;
    u.h = v; w.i = __shfl_xor(u.i, 16, 64); v = v + w.h;
    u.h = v; w.i = __shfl_xor(u.i, 32, 64); v = v + w.h;
    return v;
}

__device__ __forceinline__ f16x4 cvt4(float4 w) {
    f16x2 a = pk(w.x, w.y);
    f16x2 b = pk(w.z, w.w);
    f16x4 r; r[0] = a[0]; r[1] = a[1]; r[2] = b[0]; r[3] = b[1];
    return r;
}

// grid: 512 blocks = 256 n-groups (8 n) x 2 b-groups (128 b); 512 thr = 8 waves.
// MODE = -1: fused (all 3 passes + epilogue, cooperative).  MODE = 0/1/2:
// single pass p (fallback path, no grid.sync).
template<int MODE>
__global__ __launch_bounds__(512, 4)
void caps_k(const float* __restrict__ poses, const float* __restrict__ weight,
            const float* __restrict__ bias,
            float* __restrict__ s0, float* __restrict__ s1,
            float* __restrict__ s2, float* __restrict__ out)
{
    __shared__ f16   Ws[1280 * 16];   // 40960 B: 8 n x 10 c x 16 rows, swizzled cols
    __shared__ float tr[8 * 320];     // 10240 B: per-wave transpose scratch

    const int tid  = threadIdx.x;
    const int blk  = blockIdx.x;
    const int ngrp = blk >> 1;          // 256 n-groups (8 n each)
    const int b0   = (blk & 1) * 128;   // 2 b-groups
    const int wave = tid >> 6;
    const int lane = tid & 63;
    const int q    = lane >> 4;
    const int lo   = lane & 15;
    const int bg   = b0 + wave * 16;    // wave's global batch base

    // read-side swizzle (lane-constant, R16-verified): physical col-quad =
    // q ^ sigma(row), sigma(row)&3 = sr ^ 2*(c&1) for row=(n*10+c)*16+lo.
    const int sr  = ((lo >> 1) ^ (lo >> 3)) & 3;
    const int xqE = ((q ^ sr) & 3) * 4;          // even c
    const int xqO = ((q ^ sr ^ 2) & 3) * 4;      // odd c

    // ---- one-time weight staging: 8n slice = 5120 float4, 10 per thread.
    // store col swizzle: for f = tid + k*512, row = f>>2 = (tid>>2)+128k ->
    // sigma(row) = ((tid>>3)^(tid>>5))&3, k-invariant (bit-disjoint adds).
    {
        const float* wp = weight + (size_t)ngrp * 20480;   // 8n x 160 x 16 f32
        const int wcol = (((tid & 3) ^ ((tid >> 3) ^ (tid >> 5))) & 3) * 4;
        float4 wtmp[10];
        #pragma unroll
        for (int k = 0; k < 10; ++k)
            wtmp[k] = ((const float4*)wp)[tid + k * 512];
        #pragma unroll
        for (int k = 0; k < 10; ++k) {
            const int f = tid + k * 512;          // float4 index in [0,5120)
            *(f16x4*)&Ws[(f >> 2) * 16 + wcol] = cvt4(wtmp[k]);
        }
    }

    // ---- poses: each lane holds its own 8 MFMA B-fragments (R18-verified map).
    // bxh[n] = f16(poses[b=bg+lo][ngrp*8+n][i=q*4..q*4+3])
    f16x4 bxh[8];
    {
        const float4* pp = (const float4*)poses;
        const size_t rowb = (size_t)(bg + lo) * 8192 + q;    // float4 units
        #pragma unroll
        for (int n = 0; n < 8; ++n)
            bxh[n] = cvt4(pp[rowb + (size_t)(ngrp * 8 + n) * 4]);
    }

    __syncthreads();   // Ws visible to all waves

    const int p_first = (MODE < 0) ? 0 : MODE;
    const int p_last  = (MODE < 0) ? 2 : MODE;

    #pragma unroll 1
    for (int pass = p_first; pass <= p_last; ++pass) {
        float* dst = (pass == 0) ? s0 : (pass == 1) ? s1 : s2;
        const float fs = (pass == 0) ? 0.1f : 1.f;

        // ---- inline squash: vsp[c] = v[b=bg+lo][c][o=q*4..q*4+3], packed f16
        f16x2 vsp[10][2];
        if (pass >= 1) {
            const int rowb = (bg + lo) * 10;
            #pragma unroll
            for (int c = 0; c < 10; ++c) {
                float4 bb = *(const float4*)(bias + c * 16 + q * 4);
                const size_t off = (size_t)(rowb + c) * 16 + q * 4;
                float4 sa = *(const float4*)(s0 + off);
                float t0 = sa.x + bb.x, t1 = sa.y + bb.y;
                float t2 = sa.z + bb.z, t3 = sa.w + bb.w;
                float n2 = xorsum4(t0*t0 + t1*t1 + t2*t2 + t3*t3);
                float sc = n2 / (1.f + n2) * rsqrtf(n2 + 1e-8f);
                float v0 = sc*t0, v1 = sc*t1, v2 = sc*t2, v3 = sc*t3;
                if (pass == 2) {
                    float4 ua = *(const float4*)(s1 + off);
                    float u0 = ua.x + bb.x, u1 = ua.y + bb.y;
                    float u2 = ua.z + bb.z, u3 = ua.w + bb.w;
                    float m2 = xorsum4(u0*u0 + u1*u1 + u2*u2 + u3*u3);
                    float sc2 = m2 / (1.f + m2) * rsqrtf(m2 + 1e-8f);
                    v0 += sc2*u0; v1 += sc2*u1; v2 += sc2*u2; v3 += sc2*u3;
                }
                vsp[c][0] = pk(v0, v1);
                vsp[c][1] = pk(v2, v3);
            }
        }

        f32x4 acc[10];
        #pragma unroll
        for (int c = 0; c < 10; ++c) acc[c] = (f32x4){0.f, 0.f, 0.f, 0.f};

        #pragma unroll 2
        for (int n = 0; n < 8; ++n) {
            // votes^T fragments V[c][r] = votes[b=bg+lo][c][o=q*4+r] (R7 layout)
            f16x4 bx = bxh[n];
            f16x2 Vh[10][2];
            #pragma unroll
            for (int c = 0; c < 10; ++c) {
                f16x4 aw = *(const f16x4*)&Ws[((n * 10 + c) * 16 + lo) * 16
                                              + ((c & 1) ? xqO : xqE)];
                f32x4 V = __builtin_amdgcn_mfma_f32_16x16x16f16(
                    aw, bx, (f32x4){0.f, 0.f, 0.f, 0.f}, 0, 0, 0);
                Vh[c][0] = pk(V[0], V[1]);
                Vh[c][1] = pk(V[2], V[3]);
            }

            float cfv[10];
            if (pass >= 1) {
                float lg[10];
                #pragma unroll
                for (int cp = 0; cp < 5; ++cp) {
                    const int c0 = cp * 2, c1 = cp * 2 + 1;
                    float p0 = FDOT2(Vh[c0][0], vsp[c0][0], 0.f);
                    p0 = FDOT2(Vh[c0][1], vsp[c0][1], p0);
                    float p1 = FDOT2(Vh[c1][0], vsp[c1][0], 0.f);
                    p1 = FDOT2(Vh[c1][1], vsp[c1][1], p1);
                    f16x2 pr = xorsum4h(pk(p0, p1));
                    lg[c0] = (float)pr[0];
                    lg[c1] = (float)pr[1];
                }
                float m = lg[0];
                #pragma unroll
                for (int c = 1; c < 10; ++c) m = fmaxf(m, lg[c]);
                float sum = 0.f;
                #pragma unroll
                for (int c = 0; c < 10; ++c) { lg[c] = __expf(lg[c] - m); sum += lg[c]; }
                const float inv = 1.f / sum;
                #pragma unroll
                for (int c = 0; c < 10; ++c) cfv[c] = lg[c] * inv;
            }

            #pragma unroll
            for (int c = 0; c < 10; ++c) {
                const float w = (pass == 0) ? 1.f : cfv[c];
                acc[c][0] = fmaf(w, (float)Vh[c][0][0], acc[c][0]);
                acc[c][1] = fmaf(w, (float)Vh[c][0][1], acc[c][1]);
                acc[c][2] = fmaf(w, (float)Vh[c][1][0], acc[c][2]);
                acc[c][3] = fmaf(w, (float)Vh[c][1][1], acc[c][3]);
            }
        }

        // ---- wave-local LDS transpose (b<->o) + full-line atomic flush.
        // tr is a dedicated per-wave buffer: wave-synchronous in-order DS ops.
        float* trw = tr + wave * 320;    // 320 floats/wave, stride-20 rows
        #pragma unroll
        for (int c = 0; c < 10; ++c) {
            *(float4*)&trw[lo * 20 + q * 4] =
                (float4){acc[c][0], acc[c][1], acc[c][2], acc[c][3]};
            float r0 = trw[(q * 4 + 0) * 20 + lo];
            float r1 = trw[(q * 4 + 1) * 20 + lo];
            float r2 = trw[(q * 4 + 2) * 20 + lo];
            float r3 = trw[(q * 4 + 3) * 20 + lo];
            float* sp = dst + ((size_t)(bg + q * 4) * 10 + c) * 16 + lo;
            unsafeAtomicAdd(sp + 0 * 160, fs * r0);
            unsafeAtomicAdd(sp + 1 * 160, fs * r1);
            unsafeAtomicAdd(sp + 2 * 160, fs * r2);
            unsafeAtomicAdd(sp + 3 * 160, fs * r3);
        }

        if constexpr (MODE < 0) {
            __threadfence();
            cg::this_grid().sync();
        }
    }

    // ---- epilogue squash (fused mode only): 2560 rows, one (b,c) per thread.
    if constexpr (MODE < 0) {
        const int t = blk * 512 + tid;
        if (t < 2560) {
            const int c = t % 10;
            const float* sp = s2 + (size_t)t * 16;
            const float* bp = bias + c * 16;
            float sv[16];
            float n2 = 0.f;
            #pragma unroll
            for (int o = 0; o < 16; ++o) { float v = sp[o] + bp[o]; sv[o] = v; n2 += v * v; }
            const float scale = n2 / (1.f + n2) * rsqrtf(n2 + 1e-8f);
            float a2 = 0.f;
            #pragma unroll
            for (int o = 0; o < 16; ++o) {
                float v = scale * sv[o];
                out[(size_t)t * 16 + o] = v;
                a2 += v * v;
            }
            out[40960 + t] = sqrtf(a2 + 1e-8f);
        }
    }
}

// standalone epilogue for the non-cooperative fallback path.
__global__ __launch_bounds__(256)
void epi_k(const float* __restrict__ s2, const float* __restrict__ bias,
           float* __restrict__ out)
{
    const int t = blockIdx.x * 256 + threadIdx.x;
    if (t >= 2560) return;
    const int c = t % 10;
    const float* sp = s2 + (size_t)t * 16;
    const float* bp = bias + c * 16;
    float sv[16];
    float n2 = 0.f;
    #pragma unroll
    for (int o = 0; o < 16; ++o) { float v = sp[o] + bp[o]; sv[o] = v; n2 += v * v; }
    const float scale = n2 / (1.f + n2) * rsqrtf(n2 + 1e-8f);
    float a2 = 0.f;
    #pragma unroll
    for (int o = 0; o < 16; ++o) {
        float v = scale * sv[o];
        out[(size_t)t * 16 + o] = v;
        a2 += v * v;
    }
    out[40960 + t] = sqrtf(a2 + 1e-8f);
}

extern "C" void kernel_launch(void* const* d_in, const int* in_sizes, int n_in,
                              void* d_out, int out_size, void* d_ws, size_t ws_size,
                              hipStream_t stream)
{
    const float* poses  = (const float*)d_in[0];
    // d_in[1] (input_caps_activations) unused by the reference.
    const float* weight = (const float*)d_in[2];
    const float* bias   = (const float*)d_in[3];
    float* out = (float*)d_out;
    float* s0 = (float*)d_ws;
    float* s1 = s0 + 40960;
    float* s2 = s1 + 40960;

    (void)hipMemsetAsync(d_ws, 0, 3 * 40960 * sizeof(float), stream);

    void* args[] = {(void*)&poses, (void*)&weight, (void*)&bias,
                    (void*)&s0, (void*)&s1, (void*)&s2, (void*)&out};
    hipError_t err = hipLaunchCooperativeKernel((const void*)caps_k<-1>,
                                                dim3(512), dim3(512),
                                                args, 0, stream);
    if (err != hipSuccess) {
        // fallback: 3 single-pass launches of the same kernel + epilogue.
        caps_k<0><<<512, 512, 0, stream>>>(poses, weight, bias, s0, s1, s2, out);
        caps_k<1><<<512, 512, 0, stream>>>(poses, weight, bias, s0, s1, s2, out);
        caps_k<2><<<512, 512, 0, stream>>>(poses, weight, bias, s0, s1, s2, out);
        epi_k<<<10, 256, 0, stream>>>(s2, bias, out);
    }
}

// Round 8
// 201.526 us; speedup vs baseline: 9.3225x; 9.3225x over previous
//
#include <hip/hip_runtime.h>
#include <hip/hip_fp16.h>
#include <math.h>

// LinearCaps2d, BATCH=256, N = B_TYPES*H*W = 2048, C=10, POSE=16, 3 routing iters.
// R20 = R12 (the 203.5us verified best) + ONE surgical change: weight-load hoist.
// Session evidence (R13-R19): every structural change regressed --
//   * launch_bounds 2nd arg is a MINIMUM; compiler aims higher occupancy and
//     spills: (256,4)->64regs/628MB, (256,3)->84/330MB, (512,4)->64/4.1GB.
//     (256,2)->128 regs is the only proven spill-free point. DO NOT TOUCH.
//   * per-pass time invariant to grid split (512 vs 1024), softmax presence
//     (pass0==pass2), atomic count, staging mechanism -> latency-bound body.
//   * fusion via grid.sync regressed twice (R17 298us steady + 41ms outlier;
//     R19 spill-amplified 1879us). Abandoned.
// R20 change: split load_iter into load_w/load_x and issue the 10 long-latency
// weight loads BEFORE the vsp/squash preamble (passes 1-2 only have one):
// ~500cy of HBM latency hides under the preamble's loads+shuffles+math (G15
// issue-early pattern). Live set during vsp ~= wreg(40)+vsp(20)+temps(~30) <128.
// Pass 0 is structurally identical to R12.
// ws: s0,s1,s2 [40960] f32.

typedef _Float16 f16;
typedef _Float16 f16x2 __attribute__((ext_vector_type(2)));
typedef _Float16 f16x4 __attribute__((ext_vector_type(4)));
typedef __fp16   h16x2 __attribute__((ext_vector_type(2)));
typedef float f32x4 __attribute__((ext_vector_type(4)));

__device__ __forceinline__ f16x2 pk(float a, float b) {
    h16x2 t = __builtin_amdgcn_cvt_pkrtz(a, b);
    return __builtin_bit_cast(f16x2, t);
}

#if __has_builtin(__builtin_amdgcn_fdot2)
__device__ __forceinline__ float FDOT2(f16x2 a, f16x2 b, float c) {
    return __builtin_amdgcn_fdot2(__builtin_bit_cast(h16x2, a),
                                  __builtin_bit_cast(h16x2, b), c, false);
}
#else
__device__ __forceinline__ float FDOT2(f16x2 a, f16x2 b, float c) {
    return c + (float)a[0] * (float)b[0] + (float)a[1] * (float)b[1];
}
#endif

constexpr int WS_ROW = 28;   // f16 row stride (16 i + 12 pad) -- R7's low-conflict value
constexpr int XS_ROW = 76;   // f16 row stride (4n x 16 i + pad)

__device__ __forceinline__ float xorsum4(float v) {
    v += __shfl_xor(v, 16, 64);
    v += __shfl_xor(v, 32, 64);
    return v;
}

// packed f16x2 cross-quad reduction: one shfl pair for two c's (verified R11)
__device__ __forceinline__ f16x2 xorsum4h(f16x2 v) {
    union { f16x2 h; int i; } u;
    union { int i; f16x2 h; } w;
    u.h = v; w.i = __shfl_xor(u.i, 16, 64); v = v + w.h;
    u.h = v; w.i = __shfl_xor(u.i, 32, 64); v = v + w.h;
    return v;
}

__device__ __forceinline__ f16x4 cvt4(float4 w) {
    f16x2 a = pk(w.x, w.y);
    f16x2 b = pk(w.z, w.w);
    f16x4 r; r[0] = a[0]; r[1] = a[1]; r[2] = b[0]; r[3] = b[1];
    return r;
}

// grid: 512 blocks = 128 n-groups (16 n) x 4 b-groups (64 b); 256 thr = 4 waves.
template<int PASS>
__global__ __launch_bounds__(256, 2)
void pass_k(const float* __restrict__ poses, const float* __restrict__ weight,
            const float* __restrict__ bias,
            const float* __restrict__ sp0, const float* __restrict__ sp1,
            float* __restrict__ s_dst)
{
    __shared__ f16 Ws[640 * WS_ROW];   // 35840 B (also reused as transpose buffer at end)
    __shared__ f16 xs[64 * XS_ROW];    //  9728 B

    const int tid  = threadIdx.x;
    const int blk  = blockIdx.x;
    const int ngrp = blk >> 2;          // 128 n-groups (16 n each)
    const int b0   = (blk & 3) * 64;    // 4 b-groups
    const int wave = tid >> 6;
    const int lane = tid & 63;
    const int q    = lane >> 4;
    const int lo   = lane & 15;
    const int wtb  = wave * 16;
    const int bg   = b0 + wtb;          // wave's global batch base

    // ---- staging registers + loaders (declared first so load_w(0) can be
    // issued BEFORE the vsp preamble: HBM latency hides under vsp compute).
    float4 wreg[10];
    float4 xreg[4];
    const int b_loc = tid >> 2, part = tid & 3;

    auto load_w = [&](int l) {
        const float* wp = weight + (size_t)(ngrp * 4 + l) * 10240;   // 4n x 160 x 16
        #pragma unroll
        for (int k = 0; k < 10; ++k) wreg[k] = ((const float4*)wp)[tid + k * 256];
    };
    auto load_x = [&](int l) {
        const float* xp = poses + (size_t)(b0 + b_loc) * 32768
                          + (size_t)(ngrp * 16 + l * 4 + part) * 16;
        #pragma unroll
        for (int j = 0; j < 4; ++j) xreg[j] = ((const float4*)xp)[j];
    };
    auto store_iter = [&]() {
        #pragma unroll
        for (int k = 0; k < 10; ++k) {
            const int f = tid + k * 256;          // float4 index in [0,2560)
            *(f16x4*)&Ws[(f >> 2) * WS_ROW + (f & 3) * 4] = cvt4(wreg[k]);
        }
        f16* lp = xs + b_loc * XS_ROW + part * 16;
        #pragma unroll
        for (int j = 0; j < 4; ++j) *(f16x4*)&lp[j * 4] = cvt4(xreg[j]);
    };

    // R20 hoist: issue the 10 long-latency weight loads of tile 0 now.
    load_w(0);

    // ---- inline squash: vsp[c] = v[b=bg+lo][c][o=q*4..q*4+3], packed f16
    f16x2 vsp[10][2];
    if (PASS >= 1) {
        const int rowb = (bg + lo) * 10;
        #pragma unroll
        for (int c = 0; c < 10; ++c) {
            float4 bb = *(const float4*)(bias + c * 16 + q * 4);
            float4 sa = *(const float4*)(sp0 + (size_t)(rowb + c) * 16 + q * 4);
            float t0 = sa.x + bb.x, t1 = sa.y + bb.y, t2 = sa.z + bb.z, t3 = sa.w + bb.w;
            float n2 = xorsum4(t0*t0 + t1*t1 + t2*t2 + t3*t3);
            float sc = n2 / (1.f + n2) * rsqrtf(n2 + 1e-8f);
            float v0 = sc*t0, v1 = sc*t1, v2 = sc*t2, v3 = sc*t3;
            if (PASS == 2) {
                float4 sb = *(const float4*)(sp1 + (size_t)(rowb + c) * 16 + q * 4);
                float u0 = sb.x + bb.x, u1 = sb.y + bb.y, u2 = sb.z + bb.z, u3 = sb.w + bb.w;
                float m2 = xorsum4(u0*u0 + u1*u1 + u2*u2 + u3*u3);
                float sc2 = m2 / (1.f + m2) * rsqrtf(m2 + 1e-8f);
                v0 += sc2*u0; v1 += sc2*u1; v2 += sc2*u2; v3 += sc2*u3;
            }
            vsp[c][0] = pk(v0, v1);
            vsp[c][1] = pk(v2, v3);
        }
    }

    // pose loads for tile 0 (short-latency, small) issue after the preamble.
    load_x(0);

    f32x4 acc[10];
    #pragma unroll
    for (int c = 0; c < 10; ++c) acc[c] = (f32x4){0.f, 0.f, 0.f, 0.f};

    for (int l = 0; l < 4; ++l) {
        __syncthreads();
        store_iter();
        if (l + 1 < 4) { load_w(l + 1); load_x(l + 1); }
        __syncthreads();

        #pragma unroll
        for (int n = 0; n < 4; ++n) {
            // votes^T fragments V[c][r] = votes[b=bg+lo][c][o=q*4+r] (verified R7 layout),
            // packed to f16 immediately to keep register pressure low.
            f16x4 bx = *(const f16x4*)&xs[(wtb + lo) * XS_ROW + n * 16 + q * 4];
            f16x2 Vh[10][2];
            #pragma unroll
            for (int c = 0; c < 10; ++c) {
                f16x4 aw = *(const f16x4*)&Ws[((n * 10 + c) * 16 + lo) * WS_ROW + q * 4];
                f32x4 V = __builtin_amdgcn_mfma_f32_16x16x16f16(
                    aw, bx, (f32x4){0.f, 0.f, 0.f, 0.f}, 0, 0, 0);
                Vh[c][0] = pk(V[0], V[1]);
                Vh[c][1] = pk(V[2], V[3]);
            }

            float cfv[10];
            if (PASS >= 1) {
                // logits: fdot2 on packed votes vs vsp; packed cross-quad reduce
                float lg[10];
                #pragma unroll
                for (int cp = 0; cp < 5; ++cp) {
                    const int c0 = cp * 2, c1 = cp * 2 + 1;
                    float p0 = FDOT2(Vh[c0][0], vsp[c0][0], 0.f);
                    p0 = FDOT2(Vh[c0][1], vsp[c0][1], p0);
                    float p1 = FDOT2(Vh[c1][0], vsp[c1][0], 0.f);
                    p1 = FDOT2(Vh[c1][1], vsp[c1][1], p1);
                    f16x2 pr = xorsum4h(pk(p0, p1));
                    lg[c0] = (float)pr[0];
                    lg[c1] = (float)pr[1];
                }
                float m = lg[0];
                #pragma unroll
                for (int c = 1; c < 10; ++c) m = fmaxf(m, lg[c]);
                float sum = 0.f;
                #pragma unroll
                for (int c = 0; c < 10; ++c) { lg[c] = __expf(lg[c] - m); sum += lg[c]; }
                const float inv = 1.f / sum;
                #pragma unroll
                for (int c = 0; c < 10; ++c) cfv[c] = lg[c] * inv;
            }

            // s-accumulate straight from packed votes (phase B deleted)
            #pragma unroll
            for (int c = 0; c < 10; ++c) {
                const float w = (PASS == 0) ? 1.f : cfv[c];
                acc[c][0] = fmaf(w, (float)Vh[c][0][0], acc[c][0]);
                acc[c][1] = fmaf(w, (float)Vh[c][0][1], acc[c][1]);
                acc[c][2] = fmaf(w, (float)Vh[c][1][0], acc[c][2]);
                acc[c][3] = fmaf(w, (float)Vh[c][1][1], acc[c][3]);
            }
        }
    }

    // ---- wave-local LDS transpose (b<->o) to restore R7's full-line atomic flush.
    __syncthreads();                        // all waves done reading Ws/xs as f16
    float* tr = (float*)Ws + wave * 320;    // 320 floats/wave, stride-20 rows
    const float fs = (PASS == 0) ? 0.1f : 1.f;
    #pragma unroll
    for (int c = 0; c < 10; ++c) {
        // write own (b=lo, o=q*4..q*4+3); 16B-aligned b128
        *(float4*)&tr[lo * 20 + q * 4] = (float4){acc[c][0], acc[c][1], acc[c][2], acc[c][3]};
        // read (b=q*4+r, o=lo) -- wave-synchronous, in-order DS ops
        float r0 = tr[(q * 4 + 0) * 20 + lo];
        float r1 = tr[(q * 4 + 1) * 20 + lo];
        float r2 = tr[(q * 4 + 2) * 20 + lo];
        float r3 = tr[(q * 4 + 3) * 20 + lo];
        float* sp = s_dst + ((size_t)(bg + q * 4) * 10 + c) * 16 + lo;
        unsafeAtomicAdd(sp + 0 * 160, fs * r0);
        unsafeAtomicAdd(sp + 1 * 160, fs * r1);
        unsafeAtomicAdd(sp + 2 * 160, fs * r2);
        unsafeAtomicAdd(sp + 3 * 160, fs * r3);
    }
}

// final squash: 2560 rows, one (b,c) per thread (verified R3/R7).
__global__ __launch_bounds__(256)
void epi_k(const float* __restrict__ s2, const float* __restrict__ bias,
           float* __restrict__ out)
{
    const int t = blockIdx.x * 256 + threadIdx.x;
    if (t >= 2560) return;
    const int c = t % 10;
    const float* sp = s2 + (size_t)t * 16;
    const float* bp = bias + c * 16;
    float sv[16];
    float n2 = 0.f;
    #pragma unroll
    for (int o = 0; o < 16; ++o) { float v = sp[o] + bp[o]; sv[o] = v; n2 += v * v; }
    const float scale = n2 / (1.f + n2) * rsqrtf(n2 + 1e-8f);
    float a2 = 0.f;
    #pragma unroll
    for (int o = 0; o < 16; ++o) {
        float v = scale * sv[o];
        out[(size_t)t * 16 + o] = v;
        a2 += v * v;
    }
    out[40960 + t] = sqrtf(a2 + 1e-8f);
}

extern "C" void kernel_launch(void* const* d_in, const int* in_sizes, int n_in,
                              void* d_out, int out_size, void* d_ws, size_t ws_size,
                              hipStream_t stream)
{
    const float* poses  = (const float*)d_in[0];
    // d_in[1] (input_caps_activations) unused by the reference.
    const float* weight = (const float*)d_in[2];
    const float* bias   = (const float*)d_in[3];
    float* out = (float*)d_out;
    float* s0 = (float*)d_ws;
    float* s1 = s0 + 40960;
    float* s2 = s1 + 40960;

    (void)hipMemsetAsync(d_ws, 0, 3 * 40960 * sizeof(float), stream);

    pass_k<0><<<512, 256, 0, stream>>>(poses, weight, bias, nullptr, nullptr, s0);
    pass_k<1><<<512, 256, 0, stream>>>(poses, weight, bias, s0, nullptr, s1);
    pass_k<2><<<512, 256, 0, stream>>>(poses, weight, bias, s0, s1, s2);
    epi_k<<<10, 256, 0, stream>>>(s2, bias, out);
}